// Round 9
// baseline (31258.350 us; speedup 1.0000x reference)
//
#include <hip/hip_runtime.h>
#include <math.h>

#define T_STEPS 2048
#define B_SZ 32
#define F_SZ 512
#define H_SZ 512
#define H4_SZ 2048
#define NC_SZ 64
#define NBLK 64
#define RINGE 16384          // fp16 elems per ring slot (32 KB), fragment-ordered
#define FLAG_STRIDE 32       // u32s -> 128 B: one LLC line per block's flag

typedef _Float16 f16x8 __attribute__((ext_vector_type(8)));
typedef float f32x4 __attribute__((ext_vector_type(4)));

#define TIDX(l, w, rt, ct) (((((l)*4 + (w))*2 + (rt))*2 + (ct)))

// Fire-and-forget device-scope store via atomic-swap (r8 lesson): plain sc1
// stores' consumer-visibility tracked WRITE_SIZE==ring volume -> they exit L2
// and ack from deep in the memory path; that fixed ~µs exposure per iteration
// was the floor no load-side change could move (r2-r8: -8% max). Atomics
// EXECUTE AT the coherence point -> visibility = one LLC-slice op. No sc0
// (return discarded) -> no result wait; still counted by vmcnt for draining.
#define ATOMIC_STORE_U32(addr_, val_)                                           \
    asm volatile("global_atomic_swap %0, %1, off"                               \
                 :: "v"((unsigned*)(addr_)), "v"((unsigned)(val_)) : "memory")

// Batched LLC-coherent h-load (r8): fragment-ordered ring ->
// wave's 64 lanes load CONTIGUOUS 1KB per dwordx4; one vmcnt(0) for all 16.
// Ring slot layout: [kql(2)][ks(8)][rt(2)][lane(64)][i(8)] fp16.
#define LDFRAG16(d, a0, a1, a2, a3)                                             \
  asm volatile(                                                                 \
    "global_load_dwordx4 %0, %16, off sc0 sc1\n\t"                              \
    "global_load_dwordx4 %1, %16, off offset:1024 sc0 sc1\n\t"                  \
    "global_load_dwordx4 %2, %16, off offset:2048 sc0 sc1\n\t"                  \
    "global_load_dwordx4 %3, %16, off offset:3072 sc0 sc1\n\t"                  \
    "global_load_dwordx4 %4, %17, off sc0 sc1\n\t"                              \
    "global_load_dwordx4 %5, %17, off offset:1024 sc0 sc1\n\t"                  \
    "global_load_dwordx4 %6, %17, off offset:2048 sc0 sc1\n\t"                  \
    "global_load_dwordx4 %7, %17, off offset:3072 sc0 sc1\n\t"                  \
    "global_load_dwordx4 %8, %18, off sc0 sc1\n\t"                              \
    "global_load_dwordx4 %9, %18, off offset:1024 sc0 sc1\n\t"                  \
    "global_load_dwordx4 %10, %18, off offset:2048 sc0 sc1\n\t"                 \
    "global_load_dwordx4 %11, %18, off offset:3072 sc0 sc1\n\t"                 \
    "global_load_dwordx4 %12, %19, off sc0 sc1\n\t"                             \
    "global_load_dwordx4 %13, %19, off offset:1024 sc0 sc1\n\t"                 \
    "global_load_dwordx4 %14, %19, off offset:2048 sc0 sc1\n\t"                 \
    "global_load_dwordx4 %15, %19, off offset:3072 sc0 sc1\n\t"                 \
    "s_waitcnt vmcnt(0)"                                                        \
    : "=&v"(d[0][0]), "=&v"(d[1][0]), "=&v"(d[0][1]), "=&v"(d[1][1]),           \
      "=&v"(d[0][2]), "=&v"(d[1][2]), "=&v"(d[0][3]), "=&v"(d[1][3]),           \
      "=&v"(d[0][4]), "=&v"(d[1][4]), "=&v"(d[0][5]), "=&v"(d[1][5]),           \
      "=&v"(d[0][6]), "=&v"(d[1][6]), "=&v"(d[0][7]), "=&v"(d[1][7])            \
    : "v"(a0), "v"(a1), "v"(a2), "v"(a3)                                        \
    : "memory")

// Persistent 2-layer LSTM (r8 structure; store class + prefetch slot changed).
// 64 blocks x 256 thr. Block j owns hidden units [8j,8j+8) of BOTH layers
// (c-state in regs). Iter it: layer0 t=it, layer1 t=it-1, one flag-barrier.
__global__ __launch_bounds__(256, 1) void lstm_persistent(
    const float* __restrict__ feats,
    const float* __restrict__ Wi0, const float* __restrict__ Wh0,
    const float* __restrict__ bh0,
    const float* __restrict__ Wi1, const float* __restrict__ Wh1,
    const float* __restrict__ bh1,
    const float* __restrict__ Wout, const float* __restrict__ bout,
    float* __restrict__ out,
    _Float16* __restrict__ h0ring,  // [2][RINGE] fp16, fragment-ordered
    _Float16* __restrict__ h1ring,  // [2][RINGE] fp16, fragment-ordered
    float* __restrict__ h1fin,      // [32][512] f32 final h1
    unsigned* __restrict__ flags)   // [64 * FLAG_STRIDE] per-block flags, padded
{
    const int tid   = threadIdx.x;
    const int lane  = tid & 63;
    const int wv    = tid >> 6;          // wave 0..3 = K-quarter of stacked K=1024
    const int jb    = blockIdx.x;        // 0..63
    const int hbase = jb * 8;
    const int rlane = lane & 15;
    const int klo   = (lane >> 4) * 8;

    __shared__ float zs[32 * 272];       // 32 tiles of 16x17 f32 partials
    __shared__ float ps[256];

    // ---- one-time: weight fragments (fp16) ----
    // layer0 stacked K: [Wi0(512); Wh0(512)], A0 = [x | h0]
    // layer1 stacked K: [Wh1(512); Wi1(512)], A1 = [h1 | h0]
    // B frag 16x16x32: lane holds col=lane&15, k=(lane>>4)*8+i  (verified r1)
    f16x8 wf0[2][8], wf1[2][8];
    #pragma unroll
    for (int ct = 0; ct < 2; ++ct) {
        const int cc   = ct * 16 + rlane;
        const int jcol = (cc >> 3) * H_SZ + hbase + (cc & 7);
        #pragma unroll
        for (int ks = 0; ks < 8; ++ks) {
            const int k0 = 256 * wv + 32 * ks + klo;
            f16x8 f0, f1;
            #pragma unroll
            for (int i = 0; i < 8; ++i) {
                const int k = k0 + i;
                const float v0 = (k < H_SZ) ? Wi0[(size_t)k * H4_SZ + jcol]
                                            : Wh0[(size_t)(k - H_SZ) * H4_SZ + jcol];
                const float v1 = (k < H_SZ) ? Wh1[(size_t)k * H4_SZ + jcol]
                                            : Wi1[(size_t)(k - H_SZ) * H4_SZ + jcol];
                f0[i] = (_Float16)v0;
                f1[i] = (_Float16)v1;
            }
            wf0[ct][ks] = f0;
            wf1[ct][ks] = f1;
        }
    }

    // gate-thread mapping: all 256 threads, one (batch,unit) each
    const int gb = tid >> 3, gu = tid & 7;
    const int grow = gb & 15, grt = gb >> 4;
    float c0 = 0.f, c1 = 0.f;
    float bias0[4], bias1[4];
    #pragma unroll
    for (int g = 0; g < 4; ++g) {
        bias0[g] = bh0[g * H_SZ + hbase + gu];
        bias1[g] = bh1[g * H_SZ + hbase + gu];
    }
    // producer scatter index into fragment-ordered ring for value (b=gb,
    // u=hbase+gu): kql=jb>>5, ks=(jb>>2)&7, lane=(jb&3)*16+(gb&15), rt=gb>>4
    const int eidx = (jb >> 5) * 8192
                   + ((((jb >> 2) & 7) * 2) + (gb >> 4)) * 512
                   + ((jb & 3) * 16 + (gb & 15)) * 8 + gu;

    f16x8 xf[2][8];   // prefetched+converted x fragments (waves 0,1)

#define PREFETCH_X(tt_) do {                                                         \
    if (wv < 2 && (tt_) < T_STEPS) {                                                 \
        _Pragma("unroll")                                                            \
        for (int rt = 0; rt < 2; ++rt) {                                             \
            const float* xr = feats                                                  \
                + ((size_t)(rt * 16 + rlane) * T_STEPS + (size_t)(tt_)) * F_SZ       \
                + 256 * wv + klo;                                                    \
            _Pragma("unroll")                                                        \
            for (int ks = 0; ks < 8; ++ks) {                                         \
                const float4 p0 = *(const float4*)(xr + 32 * ks);                    \
                const float4 p1 = *(const float4*)(xr + 32 * ks + 4);                \
                f16x8 t;                                                             \
                t[0] = (_Float16)p0.x; t[1] = (_Float16)p0.y;                        \
                t[2] = (_Float16)p0.z; t[3] = (_Float16)p0.w;                        \
                t[4] = (_Float16)p1.x; t[5] = (_Float16)p1.y;                        \
                t[6] = (_Float16)p1.z; t[7] = (_Float16)p1.w;                        \
                xf[rt][ks] = t;                                                      \
            }                                                                        \
        }                                                                            \
    }                                                                                \
} while (0)

    PREFETCH_X(0);

    for (int it = 0; it <= T_STEPS; ++it) {
        // ---- distributed barrier: each poll lane owns one padded flag line ----
        // (prefetch no longer outstanding here — its vmcnt was retired by the
        // previous iteration's drain — so each poll waits only on its own load)
        if (tid < 64) {
            while (__hip_atomic_load(&flags[(size_t)lane * FLAG_STRIDE],
                                     __ATOMIC_RELAXED, __HIP_MEMORY_SCOPE_AGENT)
                   < (unsigned)it) { }
        }
        __syncthreads();

        // ---- h fragments: fully-coalesced fragment-ordered loads ----
        // wv>=2: h0[it-1] slot (it+1)&1, kql=wv-2 (shared by layer0 & layer1)
        // wv<2 : h1[it-2] slot it&1,     kql=wv
        f16x8 hA[2][8];
        if (wv >= 2) {
            const _Float16* b = h0ring + (size_t)((it + 1) & 1) * RINGE
                                + (wv - 2) * 8192 + lane * 8;
            LDFRAG16(hA, b, b + 2048, b + 4096, b + 6144);
        } else if (it > 0) {
            const _Float16* b = h1ring + (size_t)(it & 1) * RINGE
                                + wv * 8192 + lane * 8;
            LDFRAG16(hA, b, b + 2048, b + 4096, b + 6144);
        }

        const int r0 = (lane >> 4) * 4, ccl = lane & 15;

        // ---- layer0 MFMA (t=it): A = x (wv<2, in regs) or h0 (wv>=2) ----
        if (it < T_STEPS) {
            f32x4 a00 = {0,0,0,0}, a01 = {0,0,0,0}, a10 = {0,0,0,0}, a11 = {0,0,0,0};
            #pragma unroll
            for (int ks = 0; ks < 8; ++ks) {
                const f16x8 ar0 = (wv < 2) ? xf[0][ks] : hA[0][ks];
                const f16x8 ar1 = (wv < 2) ? xf[1][ks] : hA[1][ks];
                a00 = __builtin_amdgcn_mfma_f32_16x16x32_f16(ar0, wf0[0][ks], a00, 0, 0, 0);
                a01 = __builtin_amdgcn_mfma_f32_16x16x32_f16(ar0, wf0[1][ks], a01, 0, 0, 0);
                a10 = __builtin_amdgcn_mfma_f32_16x16x32_f16(ar1, wf0[0][ks], a10, 0, 0, 0);
                a11 = __builtin_amdgcn_mfma_f32_16x16x32_f16(ar1, wf0[1][ks], a11, 0, 0, 0);
            }
            #pragma unroll
            for (int q = 0; q < 4; ++q) {
                zs[TIDX(0, wv, 0, 0) * 272 + (r0 + q) * 17 + ccl] = a00[q];
                zs[TIDX(0, wv, 0, 1) * 272 + (r0 + q) * 17 + ccl] = a01[q];
                zs[TIDX(0, wv, 1, 0) * 272 + (r0 + q) * 17 + ccl] = a10[q];
                zs[TIDX(0, wv, 1, 1) * 272 + (r0 + q) * 17 + ccl] = a11[q];
            }
        }

        // ---- prefetch x[it+1] in the xf-dead slot (consumed by layer0 above;
        // loads complete under layer1 MFMA + gates instead of polluting the
        // next barrier poll's vmcnt(0) — r8 had it on the poll's critical path)
        PREFETCH_X(it + 1);

        // ---- layer1 MFMA (t=it-1): A = h1 (wv<2) or h0 (wv>=2) = hA ----
        if (it > 0) {
            f32x4 a00 = {0,0,0,0}, a01 = {0,0,0,0}, a10 = {0,0,0,0}, a11 = {0,0,0,0};
            #pragma unroll
            for (int ks = 0; ks < 8; ++ks) {
                a00 = __builtin_amdgcn_mfma_f32_16x16x32_f16(hA[0][ks], wf1[0][ks], a00, 0, 0, 0);
                a01 = __builtin_amdgcn_mfma_f32_16x16x32_f16(hA[0][ks], wf1[1][ks], a01, 0, 0, 0);
                a10 = __builtin_amdgcn_mfma_f32_16x16x32_f16(hA[1][ks], wf1[0][ks], a10, 0, 0, 0);
                a11 = __builtin_amdgcn_mfma_f32_16x16x32_f16(hA[1][ks], wf1[1][ks], a11, 0, 0, 0);
            }
            #pragma unroll
            for (int q = 0; q < 4; ++q) {
                zs[TIDX(1, wv, 0, 0) * 272 + (r0 + q) * 17 + ccl] = a00[q];
                zs[TIDX(1, wv, 0, 1) * 272 + (r0 + q) * 17 + ccl] = a01[q];
                zs[TIDX(1, wv, 1, 0) * 272 + (r0 + q) * 17 + ccl] = a10[q];
                zs[TIDX(1, wv, 1, 1) * 272 + (r0 + q) * 17 + ccl] = a11[q];
            }
        }
        __syncthreads();

        // ---- gates: reduce 4 K-partials, update c, ATOMIC-SWAP h into ring ----
        if (it < T_STEPS) {
            float z[4];
            #pragma unroll
            for (int g = 0; g < 4; ++g) {
                const int cc = g * 8 + gu, ct = cc >> 4, col = cc & 15;
                float v = bias0[g];
                #pragma unroll
                for (int w = 0; w < 4; ++w)
                    v += zs[TIDX(0, w, grt, ct) * 272 + grow * 17 + col];
                z[g] = v;
            }
            const float ig = 1.f / (1.f + expf(-z[0]));
            const float fg = 1.f / (1.f + expf(-z[1]));
            const float gg = tanhf(z[2]);
            const float og = 1.f / (1.f + expf(-z[3]));
            c0 = fg * c0 + ig * gg;
            const float hv = og * tanhf(c0);
            const float hpart = __shfl_xor(hv, 1);
            if ((gu & 1) == 0) {   // pack 2 fp16 (eidx consecutive in gu) -> u32 swap
                union { _Float16 h[2]; unsigned u; } pk;
                pk.h[0] = (_Float16)hv; pk.h[1] = (_Float16)hpart;
                ATOMIC_STORE_U32(h0ring + (size_t)(it & 1) * RINGE + eidx, pk.u);
            }
        }
        if (it > 0) {
            float z[4];
            #pragma unroll
            for (int g = 0; g < 4; ++g) {
                const int cc = g * 8 + gu, ct = cc >> 4, col = cc & 15;
                float v = bias1[g];
                #pragma unroll
                for (int w = 0; w < 4; ++w)
                    v += zs[TIDX(1, w, grt, ct) * 272 + grow * 17 + col];
                z[g] = v;
            }
            const float ig = 1.f / (1.f + expf(-z[0]));
            const float fg = 1.f / (1.f + expf(-z[1]));
            const float gg = tanhf(z[2]);
            const float og = 1.f / (1.f + expf(-z[3]));
            c1 = fg * c1 + ig * gg;
            const float hv = og * tanhf(c1);
            const float hpart = __shfl_xor(hv, 1);
            if ((gu & 1) == 0) {
                union { _Float16 h[2]; unsigned u; } pk;
                pk.h[0] = (_Float16)hv; pk.h[1] = (_Float16)hpart;
                ATOMIC_STORE_U32(h1ring + (size_t)((it + 1) & 1) * RINGE + eidx, pk.u);
            }
            if (it == T_STEPS) {
                union { float f; unsigned u; } cf; cf.f = hv;
                ATOMIC_STORE_U32(h1fin + gb * H_SZ + hbase + gu, cf.u);
            }
        }
        // drain atomics (vmcnt counts them) then arrive via atomic flag swap
        asm volatile("s_waitcnt vmcnt(0)" ::: "memory");
        __syncthreads();
        if (tid == 0)
            ATOMIC_STORE_U32(&flags[(size_t)jb * FLAG_STRIDE], (unsigned)(it + 1));
    }

    // final barrier: all h1fin atomics visible
    if (tid < 64) {
        while (__hip_atomic_load(&flags[(size_t)lane * FLAG_STRIDE],
                                 __ATOMIC_RELAXED, __HIP_MEMORY_SCOPE_AGENT)
               < (unsigned)(T_STEPS + 1)) { }
    }
    __syncthreads();

    // ---- output head: block jb -> out[:, jb] ----
    {
        const int b = tid & 31, kc = tid >> 5;
        float part = 0.f;
        for (int k = kc * 64; k < kc * 64 + 64; ++k) {
            union { unsigned u; float f; } cv;
            cv.u = __hip_atomic_load((const unsigned*)(h1fin + b * H_SZ + k),
                                     __ATOMIC_RELAXED, __HIP_MEMORY_SCOPE_AGENT);
            part += cv.f * Wout[(size_t)k * NC_SZ + jb];
        }
        ps[kc * 32 + b] = part;
        __syncthreads();
        if (tid < 32) {
            float acc = bout[jb];
            #pragma unroll
            for (int c = 0; c < 8; ++c) acc += ps[c * 32 + tid];
            out[tid * NC_SZ + jb] = acc;
        }
    }
#undef PREFETCH_X
}

extern "C" void kernel_launch(void* const* d_in, const int* in_sizes, int n_in,
                              void* d_out, int out_size, void* d_ws, size_t ws_size,
                              hipStream_t stream) {
    const float* feats = (const float*)d_in[0];
    const float* Wi0   = (const float*)d_in[1];
    const float* Wh0   = (const float*)d_in[2];
    const float* bh0   = (const float*)d_in[3];
    const float* Wi1   = (const float*)d_in[4];
    const float* Wh1   = (const float*)d_in[5];
    const float* bh1   = (const float*)d_in[6];
    const float* Wout  = (const float*)d_in[7];
    const float* bout  = (const float*)d_in[8];

    char* ws = (char*)d_ws;
    _Float16* h0ring = (_Float16*)(ws);           // 2 slots * 32 KB
    _Float16* h1ring = (_Float16*)(ws + 131072);  // 2 slots * 32 KB
    float*    h1fin  = (float*)(ws + 262144);     // 64 KB
    unsigned* flags  = (unsigned*)(ws + 327680);  // 64 * 128 B = 8 KB

    // zero rings (h[-1]=h[-2]=0), final buf, flags — every call (determinism;
    // graph replays reuse ws, so stale flags MUST be cleared each call)
    hipMemsetAsync(d_ws, 0, 335872, stream);

    lstm_persistent<<<dim3(NBLK), dim3(256), 0, stream>>>(
        feats, Wi0, Wh0, bh0, Wi1, Wh1, bh1, Wout, bout,
        (float*)d_out, h0ring, h1ring, h1fin, flags);
}

// Round 10
// 28964.954 us; speedup vs baseline: 1.0792x; 1.0792x over previous
//
#include <hip/hip_runtime.h>
#include <math.h>

#define T_STEPS 2048
#define B_SZ 32
#define F_SZ 512
#define H_SZ 512
#define H4_SZ 2048
#define NC_SZ 64
#define NBLK 64
#define SLOT_U32 16384       // tagged u32 words per ring slot (64 KB)

typedef _Float16 f16x8 __attribute__((ext_vector_type(8)));
typedef float f32x4 __attribute__((ext_vector_type(4)));
typedef unsigned u32x4 __attribute__((ext_vector_type(4)));

#define TIDX(l, w, rt, ct) (((((l)*4 + (w))*2 + (rt))*2 + (ct)))

// r10 = r4 (tag-dataflow, no barrier/drain/flags) x r8 (fragment-ordered
// coalescing). Ring word u32 = (epoch_tag << 16) | fp16_bits(h): one 4B store
// is atomic, so tag-fresh <=> value-fresh. Producer NEVER waits (no vmcnt
// drain, no flag store); consumer's poll IS the data load. Chain per step:
// visibility (~1 RTT) + <=1 retry quantum, vs r3-r9's 4-RTT chain
// (drain -> flag -> poll -> load) that pinned 13us/iter.
// Slot layout (u32): [kql(2)][ks(8)][rt(2)][pair(2)][lane(64)][q(4)]
// -> consumer dwordx4 at lane*16B is FULLY dense (1KB/instr, r7/r8 lesson:
// request efficiency is the only lever that ever moved the floor).
// Safety (r4 argument, re-checked): depth-2 ring + tags is a distributed
// barrier — block P reaches epoch e's gates only after P's reads of e-1
// succeeded, and every block's e-1 slice was written only after that block
// read ALL of e-2; so e's overwrite of e-2's slot is strictly ordered after
// every block's successful read of e-2.
#define LDQ16(w_, b0_, b1_, b2_, b3_)                                           \
  asm volatile(                                                                 \
    "global_load_dwordx4 %0, %16, off sc0 sc1\n\t"                              \
    "global_load_dwordx4 %1, %16, off offset:1024 sc0 sc1\n\t"                  \
    "global_load_dwordx4 %2, %16, off offset:2048 sc0 sc1\n\t"                  \
    "global_load_dwordx4 %3, %16, off offset:3072 sc0 sc1\n\t"                  \
    "global_load_dwordx4 %4, %17, off sc0 sc1\n\t"                              \
    "global_load_dwordx4 %5, %17, off offset:1024 sc0 sc1\n\t"                  \
    "global_load_dwordx4 %6, %17, off offset:2048 sc0 sc1\n\t"                  \
    "global_load_dwordx4 %7, %17, off offset:3072 sc0 sc1\n\t"                  \
    "global_load_dwordx4 %8, %18, off sc0 sc1\n\t"                              \
    "global_load_dwordx4 %9, %18, off offset:1024 sc0 sc1\n\t"                  \
    "global_load_dwordx4 %10, %18, off offset:2048 sc0 sc1\n\t"                 \
    "global_load_dwordx4 %11, %18, off offset:3072 sc0 sc1\n\t"                 \
    "global_load_dwordx4 %12, %19, off sc0 sc1\n\t"                             \
    "global_load_dwordx4 %13, %19, off offset:1024 sc0 sc1\n\t"                 \
    "global_load_dwordx4 %14, %19, off offset:2048 sc0 sc1\n\t"                 \
    "global_load_dwordx4 %15, %19, off offset:3072 sc0 sc1\n\t"                 \
    "s_waitcnt vmcnt(0)"                                                        \
    : "=&v"(w_[0]), "=&v"(w_[1]), "=&v"(w_[2]), "=&v"(w_[3]),                   \
      "=&v"(w_[4]), "=&v"(w_[5]), "=&v"(w_[6]), "=&v"(w_[7]),                   \
      "=&v"(w_[8]), "=&v"(w_[9]), "=&v"(w_[10]), "=&v"(w_[11]),                 \
      "=&v"(w_[12]), "=&v"(w_[13]), "=&v"(w_[14]), "=&v"(w_[15])                \
    : "v"(b0_), "v"(b1_), "v"(b2_), "v"(b3_)                                    \
    : "memory")

// Poll+load+unpack: two halves (ks 0-3, 4-7); each half retries its 16-load
// burst until every tag matches, then unpacks low-16 payloads into f16x8.
#define POLL_H(ring_, slot_, kql_, tag_) do {                                        \
    const unsigned* base_ = (ring_) + (size_t)(slot_) * SLOT_U32                     \
                            + (kql_) * 8192 + lane * 4;                              \
    const unsigned tg_ = (unsigned)(tag_);                                           \
    _Pragma("unroll")                                                                \
    for (int hf_ = 0; hf_ < 2; ++hf_) {                                              \
        const unsigned* b0_ = base_ + hf_ * 4096;                                    \
        const unsigned* b1_ = b0_ + 1024;                                            \
        const unsigned* b2_ = b0_ + 2048;                                            \
        const unsigned* b3_ = b0_ + 3072;                                            \
        u32x4 w_[16];                                                                \
        unsigned diff_;                                                              \
        do {                                                                         \
            LDQ16(w_, b0_, b1_, b2_, b3_);                                           \
            diff_ = 0;                                                               \
            _Pragma("unroll")                                                        \
            for (int q_ = 0; q_ < 16; ++q_)                                          \
                diff_ |= ((w_[q_][0] >> 16) ^ tg_) | ((w_[q_][1] >> 16) ^ tg_)       \
                       | ((w_[q_][2] >> 16) ^ tg_) | ((w_[q_][3] >> 16) ^ tg_);      \
            if (diff_) __builtin_amdgcn_s_sleep(1);                                  \
        } while (diff_);                                                             \
        _Pragma("unroll")                                                            \
        for (int j_ = 0; j_ < 4; ++j_) {                                             \
            const int ks_ = hf_ * 4 + j_;                                            \
            union { unsigned u[4]; f16x8 v; } r0_, r1_;                              \
            r0_.u[0] = (w_[j_*4+0][0] & 0xffffu) | (w_[j_*4+0][1] << 16);            \
            r0_.u[1] = (w_[j_*4+0][2] & 0xffffu) | (w_[j_*4+0][3] << 16);            \
            r0_.u[2] = (w_[j_*4+1][0] & 0xffffu) | (w_[j_*4+1][1] << 16);            \
            r0_.u[3] = (w_[j_*4+1][2] & 0xffffu) | (w_[j_*4+1][3] << 16);            \
            r1_.u[0] = (w_[j_*4+2][0] & 0xffffu) | (w_[j_*4+2][1] << 16);            \
            r1_.u[1] = (w_[j_*4+2][2] & 0xffffu) | (w_[j_*4+2][3] << 16);            \
            r1_.u[2] = (w_[j_*4+3][0] & 0xffffu) | (w_[j_*4+3][1] << 16);            \
            r1_.u[3] = (w_[j_*4+3][2] & 0xffffu) | (w_[j_*4+3][3] << 16);            \
            hA[0][ks_] = r0_.v;                                                      \
            hA[1][ks_] = r1_.v;                                                      \
        }                                                                            \
    }                                                                                \
} while (0)

// Dataflow persistent 2-layer LSTM: 64 blocks x 256 thr, block jb owns hidden
// units [8jb,8jb+8) of both layers; c-state in regs; weights in VGPRs.
// Iter it: layer0 t=it, layer1 t=it-1. No barriers, no flags, no drains.
__global__ __launch_bounds__(256, 1) void lstm_persistent(
    const float* __restrict__ feats,
    const float* __restrict__ Wi0, const float* __restrict__ Wh0,
    const float* __restrict__ bh0,
    const float* __restrict__ Wi1, const float* __restrict__ Wh1,
    const float* __restrict__ bh1,
    const float* __restrict__ Wout, const float* __restrict__ bout,
    float* __restrict__ out,
    unsigned* __restrict__ h0ring,  // [2][SLOT_U32] tagged u32
    unsigned* __restrict__ h1ring)  // [2][SLOT_U32] tagged u32
{
    const int tid   = threadIdx.x;
    const int lane  = tid & 63;
    const int wv    = tid >> 6;          // wave 0..3 = K-quarter of stacked K=1024
    const int jb    = blockIdx.x;        // 0..63
    const int hbase = jb * 8;
    const int rlane = lane & 15;
    const int klo   = (lane >> 4) * 8;

    __shared__ float zs[32 * 272];       // 32 tiles of 16x17 f32 partials
    __shared__ float ps[256];

    // ---- one-time: weight fragments (fp16) ----
    // layer0 stacked K: [Wi0(512); Wh0(512)], A0 = [x | h0]
    // layer1 stacked K: [Wh1(512); Wi1(512)], A1 = [h1 | h0]
    // B frag 16x16x32: lane holds col=lane&15, k=(lane>>4)*8+i  (verified r1)
    f16x8 wf0[2][8], wf1[2][8];
    #pragma unroll
    for (int ct = 0; ct < 2; ++ct) {
        const int cc   = ct * 16 + rlane;
        const int jcol = (cc >> 3) * H_SZ + hbase + (cc & 7);
        #pragma unroll
        for (int ks = 0; ks < 8; ++ks) {
            const int k0 = 256 * wv + 32 * ks + klo;
            f16x8 f0, f1;
            #pragma unroll
            for (int i = 0; i < 8; ++i) {
                const int k = k0 + i;
                const float v0 = (k < H_SZ) ? Wi0[(size_t)k * H4_SZ + jcol]
                                            : Wh0[(size_t)(k - H_SZ) * H4_SZ + jcol];
                const float v1 = (k < H_SZ) ? Wh1[(size_t)k * H4_SZ + jcol]
                                            : Wi1[(size_t)(k - H_SZ) * H4_SZ + jcol];
                f0[i] = (_Float16)v0;
                f1[i] = (_Float16)v1;
            }
            wf0[ct][ks] = f0;
            wf1[ct][ks] = f1;
        }
    }

    // gate-thread mapping: all 256 threads, one (batch,unit) each
    const int gb = tid >> 3, gu = tid & 7;
    const int grow = gb & 15, grt = gb >> 4;
    float c0 = 0.f, c1 = 0.f;
    float bias0[4], bias1[4];
    #pragma unroll
    for (int g = 0; g < 4; ++g) {
        bias0[g] = bh0[g * H_SZ + hbase + gu];
        bias1[g] = bh1[g * H_SZ + hbase + gu];
    }
    // producer word index for value (b=gb, u=hbase+gu), u32 units:
    // kql=jb>>5, ks=(jb>>2)&7, rt=gb>>4, pair=gu>>2, lane=(jb&3)*16+(gb&15), q=gu&3
    const int eidx = (jb >> 5) * 8192 + ((jb >> 2) & 7) * 1024 + (gb >> 4) * 512
                   + (gu >> 2) * 256 + ((jb & 3) * 16 + (gb & 15)) * 4 + (gu & 3);

    f16x8 xf[2][8];   // prefetched+converted x fragments (waves 0,1)

#define PREFETCH_X(tt_) do {                                                         \
    if (wv < 2 && (tt_) < T_STEPS) {                                                 \
        _Pragma("unroll")                                                            \
        for (int rt = 0; rt < 2; ++rt) {                                             \
            const float* xr = feats                                                  \
                + ((size_t)(rt * 16 + rlane) * T_STEPS + (size_t)(tt_)) * F_SZ       \
                + 256 * wv + klo;                                                    \
            _Pragma("unroll")                                                        \
            for (int ks = 0; ks < 8; ++ks) {                                         \
                const float4 p0 = *(const float4*)(xr + 32 * ks);                    \
                const float4 p1 = *(const float4*)(xr + 32 * ks + 4);                \
                f16x8 t;                                                             \
                t[0] = (_Float16)p0.x; t[1] = (_Float16)p0.y;                        \
                t[2] = (_Float16)p0.z; t[3] = (_Float16)p0.w;                        \
                t[4] = (_Float16)p1.x; t[5] = (_Float16)p1.y;                        \
                t[6] = (_Float16)p1.z; t[7] = (_Float16)p1.w;                        \
                xf[rt][ks] = t;                                                      \
            }                                                                        \
        }                                                                            \
    }                                                                                \
} while (0)

    PREFETCH_X(0);

    for (int it = 0; it <= T_STEPS; ++it) {
        // ---- tag-poll + load h fragments (per-wave; poll IS the load) ----
        // wv>=2: h0[it-1] slot (it+1)&1, kql=wv-2, tag=it   (h0[t] tag t+1)
        // wv<2 : h1[it-2] slot it&1,     kql=wv,   tag=it-1 (h1[t] tag t+1)
        f16x8 hA[2][8];
        if (wv >= 2) {
            POLL_H(h0ring, (it + 1) & 1, wv - 2, it);
        } else if (it > 0) {
            POLL_H(h1ring, it & 1, wv, it - 1);
        }

        const int r0 = (lane >> 4) * 4, ccl = lane & 15;

        // ---- layer0 MFMA (t=it): A = x (wv<2, in regs) or h0 (wv>=2) ----
        if (it < T_STEPS) {
            f32x4 a00 = {0,0,0,0}, a01 = {0,0,0,0}, a10 = {0,0,0,0}, a11 = {0,0,0,0};
            #pragma unroll
            for (int ks = 0; ks < 8; ++ks) {
                const f16x8 ar0 = (wv < 2) ? xf[0][ks] : hA[0][ks];
                const f16x8 ar1 = (wv < 2) ? xf[1][ks] : hA[1][ks];
                a00 = __builtin_amdgcn_mfma_f32_16x16x32_f16(ar0, wf0[0][ks], a00, 0, 0, 0);
                a01 = __builtin_amdgcn_mfma_f32_16x16x32_f16(ar0, wf0[1][ks], a01, 0, 0, 0);
                a10 = __builtin_amdgcn_mfma_f32_16x16x32_f16(ar1, wf0[0][ks], a10, 0, 0, 0);
                a11 = __builtin_amdgcn_mfma_f32_16x16x32_f16(ar1, wf0[1][ks], a11, 0, 0, 0);
            }
            #pragma unroll
            for (int q = 0; q < 4; ++q) {
                zs[TIDX(0, wv, 0, 0) * 272 + (r0 + q) * 17 + ccl] = a00[q];
                zs[TIDX(0, wv, 0, 1) * 272 + (r0 + q) * 17 + ccl] = a01[q];
                zs[TIDX(0, wv, 1, 0) * 272 + (r0 + q) * 17 + ccl] = a10[q];
                zs[TIDX(0, wv, 1, 1) * 272 + (r0 + q) * 17 + ccl] = a11[q];
            }
        }

        // prefetch x[it+1] in the xf-dead slot (overlaps layer1 + gates)
        PREFETCH_X(it + 1);

        // ---- layer1 MFMA (t=it-1): A = h1 (wv<2) or h0 (wv>=2) = hA ----
        if (it > 0) {
            f32x4 a00 = {0,0,0,0}, a01 = {0,0,0,0}, a10 = {0,0,0,0}, a11 = {0,0,0,0};
            #pragma unroll
            for (int ks = 0; ks < 8; ++ks) {
                a00 = __builtin_amdgcn_mfma_f32_16x16x32_f16(hA[0][ks], wf1[0][ks], a00, 0, 0, 0);
                a01 = __builtin_amdgcn_mfma_f32_16x16x32_f16(hA[0][ks], wf1[1][ks], a01, 0, 0, 0);
                a10 = __builtin_amdgcn_mfma_f32_16x16x32_f16(hA[1][ks], wf1[0][ks], a10, 0, 0, 0);
                a11 = __builtin_amdgcn_mfma_f32_16x16x32_f16(hA[1][ks], wf1[1][ks], a11, 0, 0, 0);
            }
            #pragma unroll
            for (int q = 0; q < 4; ++q) {
                zs[TIDX(1, wv, 0, 0) * 272 + (r0 + q) * 17 + ccl] = a00[q];
                zs[TIDX(1, wv, 0, 1) * 272 + (r0 + q) * 17 + ccl] = a01[q];
                zs[TIDX(1, wv, 1, 0) * 272 + (r0 + q) * 17 + ccl] = a10[q];
                zs[TIDX(1, wv, 1, 1) * 272 + (r0 + q) * 17 + ccl] = a11[q];
            }
        }
        __syncthreads();

        // ---- gates: reduce 4 K-partials, update c, fire-and-forget tagged h ----
        if (it < T_STEPS) {
            float z[4];
            #pragma unroll
            for (int g = 0; g < 4; ++g) {
                const int cc = g * 8 + gu, ct = cc >> 4, col = cc & 15;
                float v = bias0[g];
                #pragma unroll
                for (int w = 0; w < 4; ++w)
                    v += zs[TIDX(0, w, grt, ct) * 272 + grow * 17 + col];
                z[g] = v;
            }
            const float ig = 1.f / (1.f + expf(-z[0]));
            const float fg = 1.f / (1.f + expf(-z[1]));
            const float gg = tanhf(z[2]);
            const float og = 1.f / (1.f + expf(-z[3]));
            c0 = fg * c0 + ig * gg;
            const float hv = og * tanhf(c0);
            union { _Float16 h; unsigned short s; } cv; cv.h = (_Float16)hv;
            __hip_atomic_store(
                h0ring + (size_t)(it & 1) * SLOT_U32 + eidx,
                ((unsigned)(it + 1) << 16) | (unsigned)cv.s,
                __ATOMIC_RELAXED, __HIP_MEMORY_SCOPE_AGENT);
        }
        if (it > 0) {
            float z[4];
            #pragma unroll
            for (int g = 0; g < 4; ++g) {
                const int cc = g * 8 + gu, ct = cc >> 4, col = cc & 15;
                float v = bias1[g];
                #pragma unroll
                for (int w = 0; w < 4; ++w)
                    v += zs[TIDX(1, w, grt, ct) * 272 + grow * 17 + col];
                z[g] = v;
            }
            const float ig = 1.f / (1.f + expf(-z[0]));
            const float fg = 1.f / (1.f + expf(-z[1]));
            const float gg = tanhf(z[2]);
            const float og = 1.f / (1.f + expf(-z[3]));
            c1 = fg * c1 + ig * gg;
            const float hv = og * tanhf(c1);
            union { _Float16 h; unsigned short s; } cv; cv.h = (_Float16)hv;
            __hip_atomic_store(
                h1ring + (size_t)((it + 1) & 1) * SLOT_U32 + eidx,
                ((unsigned)it << 16) | (unsigned)cv.s,
                __ATOMIC_RELAXED, __HIP_MEMORY_SCOPE_AGENT);
        }
        // zs reuse protection only — NO store drain, NO flag, NO barrier
        __syncthreads();
    }

    // ---- output head: block jb -> out[:, jb]; poll tagged h1[T-1] (tag=T) ----
    {
        const unsigned* hf = h1ring + (size_t)((T_STEPS - 1) & 1) * SLOT_U32;
        const int b = tid & 31, kc = tid >> 5;
        float part = 0.f;
        for (int k = kc * 64; k < kc * 64 + 64; ++k) {
            const int widx = (k >> 8) * 8192 + ((k >> 5) & 7) * 1024
                           + (b >> 4) * 512 + ((k & 7) >> 2) * 256
                           + (((k >> 3) & 3) * 16 + (b & 15)) * 4 + (k & 3);
            unsigned w;
            do {
                w = __hip_atomic_load(hf + widx, __ATOMIC_RELAXED,
                                      __HIP_MEMORY_SCOPE_AGENT);
            } while ((w >> 16) != (unsigned)T_STEPS);
            union { unsigned short s; _Float16 h; } cv;
            cv.s = (unsigned short)(w & 0xffffu);
            part += (float)cv.h * Wout[(size_t)k * NC_SZ + jb];
        }
        ps[kc * 32 + b] = part;
        __syncthreads();
        if (tid < 32) {
            float acc = bout[jb];
            #pragma unroll
            for (int c = 0; c < 8; ++c) acc += ps[c * 32 + tid];
            out[tid * NC_SZ + jb] = acc;
        }
    }
#undef PREFETCH_X
}

extern "C" void kernel_launch(void* const* d_in, const int* in_sizes, int n_in,
                              void* d_out, int out_size, void* d_ws, size_t ws_size,
                              hipStream_t stream) {
    const float* feats = (const float*)d_in[0];
    const float* Wi0   = (const float*)d_in[1];
    const float* Wh0   = (const float*)d_in[2];
    const float* bh0   = (const float*)d_in[3];
    const float* Wi1   = (const float*)d_in[4];
    const float* Wh1   = (const float*)d_in[5];
    const float* bh1   = (const float*)d_in[6];
    const float* Wout  = (const float*)d_in[7];
    const float* bout  = (const float*)d_in[8];

    char* ws = (char*)d_ws;
    unsigned* h0ring = (unsigned*)(ws);            // 2 slots * 64 KB
    unsigned* h1ring = (unsigned*)(ws + 131072);   // 2 slots * 64 KB

    // zero rings each call: tag 0 == "epoch -1 ready", value 0 (determinism —
    // graph replays reuse ws; stale tags from the prior call MUST be cleared)
    hipMemsetAsync(d_ws, 0, 262144, stream);

    lstm_persistent<<<dim3(NBLK), dim3(256), 0, stream>>>(
        feats, Wi0, Wh0, bh0, Wi1, Wh1, bh1, Wout, bout,
        (float*)d_out, h0ring, h1ring);
}